// Round 1
// baseline (171.673 us; speedup 1.0000x reference)
//
#include <hip/hip_runtime.h>
#include <math.h>

#define BB   8
#define CC   256
#define HH   56
#define WW   56
#define KK   3
#define MIDN 51
#define NTAP (KK*KK)          // 9
#define CKK  (CC*NTAP)        // 2304
#define HW   (HH*WW)          // 3136

// ---------------- pooled mean: one block per (b,c) plane ----------------
__global__ __launch_bounds__(256) void pool_kernel(const float* __restrict__ x,
                                                   float* __restrict__ pooled) {
    int bc = blockIdx.x;
    const float* xp = x + (size_t)bc * HW;
    int t = threadIdx.x;
    float s = 0.f;
    for (int idx = t; idx < HW; idx += 256) s += xp[idx];
    for (int off = 32; off > 0; off >>= 1) s += __shfl_down(s, off, 64);
    __shared__ float red[4];
    int wave = t >> 6, lane = t & 63;
    if (lane == 0) red[wave] = s;
    __syncthreads();
    if (t == 0) pooled[bc] = (red[0] + red[1] + red[2] + red[3]) * (1.0f / HW);
}

// ---------------- tiny MLP + per-channel filter norm: one block per batch ----------------
__global__ __launch_bounds__(256) void mlp_kernel(const float* __restrict__ pooled,
                                                  const float* __restrict__ w1,
                                                  const float* __restrict__ b1,
                                                  const float* __restrict__ w2,
                                                  const float* __restrict__ b2,
                                                  const float* __restrict__ fn_std,
                                                  float* __restrict__ cf) {
    int b = blockIdx.x;
    int t = threadIdx.x;
    __shared__ float ps[CC];
    __shared__ float y1[MIDN];
    ps[t] = pooled[b * CC + t];
    __syncthreads();
    if (t < MIDN) {
        float acc = b1[t];
        const float* wr = w1 + t * CC;
        for (int c2 = 0; c2 < CC; ++c2) acc += ps[c2] * wr[c2];
        y1[t] = fmaxf(acc, 0.f);
    }
    __syncthreads();
    // thread t == channel c
    float y2[NTAP];
    const float* w2r = w2 + (size_t)t * NTAP * MIDN;
    #pragma unroll
    for (int q = 0; q < NTAP; ++q) {
        float acc = b2[t * NTAP + q];
        const float* r = w2r + q * MIDN;
        for (int m = 0; m < MIDN; ++m) acc += y1[m] * r[m];
        y2[q] = acc;
    }
    float mean = 0.f;
    #pragma unroll
    for (int q = 0; q < NTAP; ++q) mean += y2[q];
    mean *= (1.f / NTAP);
    float var = 0.f;
    #pragma unroll
    for (int q = 0; q < NTAP; ++q) { float d = y2[q] - mean; var += d * d; }
    float inv = 1.f / (sqrtf(var * (1.f / (NTAP - 1))) + 1e-10f);
    #pragma unroll
    for (int q = 0; q < NTAP; ++q) {
        int idx = t * NTAP + q;
        cf[(size_t)b * CKK + idx] = (y2[q] - mean) * inv * fn_std[idx];
    }
}

// ---------------- spatial filter: one block (64 thr) per (b, row) ----------------
__global__ __launch_bounds__(64) void sf_kernel(const float* __restrict__ x,
                                                const float* __restrict__ ws,
                                                const float* __restrict__ bs,
                                                float* __restrict__ sf) {
    int blk = blockIdx.x;            // b*HH + i
    int b = blk / HH, i = blk % HH;
    int j = threadIdx.x;
    __shared__ float wss[NTAP * CC];
    for (int idx = j; idx < NTAP * CC; idx += 64) wss[idx] = ws[idx];
    __syncthreads();
    float acc[NTAP];
    #pragma unroll
    for (int n = 0; n < NTAP; ++n) acc[n] = bs[n];
    const float* xrow = x + (size_t)b * CC * HW + i * WW;
    bool act = (j < WW);
    for (int c2 = 0; c2 < CC; ++c2) {
        float xv = act ? xrow[(size_t)c2 * HW + j] : 0.f;
        #pragma unroll
        for (int n = 0; n < NTAP; ++n) acc[n] += xv * wss[n * CC + c2];
    }
    if (act) {
        float mean = 0.f;
        #pragma unroll
        for (int n = 0; n < NTAP; ++n) mean += acc[n];
        mean *= (1.f / NTAP);
        float var = 0.f;
        #pragma unroll
        for (int n = 0; n < NTAP; ++n) { float d = acc[n] - mean; var += d * d; }
        float inv = 0.47140452079103173f /       // GAIN/K = sqrt(2)/3
                    (sqrtf(var * (1.f / (NTAP - 1))) + 1e-10f);
        #pragma unroll
        for (int n = 0; n < NTAP; ++n)
            sf[((size_t)(b * NTAP + n)) * HW + i * WW + j] = (acc[n] - mean) * inv;
    }
}

// ---------------- DDF apply: one block per (b,c) plane, LDS-staged 58x58 tile ----------------
__global__ __launch_bounds__(256) void ddf_kernel(const float* __restrict__ x,
                                                  const float* __restrict__ cf,
                                                  const float* __restrict__ sf,
                                                  float* __restrict__ out) {
    int bc = blockIdx.x;
    int b = bc / CC, c = bc % CC;
    int t = threadIdx.x;
    __shared__ float xt[58 * 58];
    for (int idx = t; idx < 58 * 58; idx += 256) xt[idx] = 0.f;
    __syncthreads();
    const float* xp = x + (size_t)bc * HW;
    for (int idx = t; idx < HW; idx += 256) {
        int r = idx / WW, col = idx - r * WW;
        xt[(r + 1) * 58 + col + 1] = xp[idx];
    }
    float cf9[NTAP];
    const float* cfp = cf + (size_t)b * CKK + c * NTAP;
    #pragma unroll
    for (int n = 0; n < NTAP; ++n) cf9[n] = cfp[n];
    __syncthreads();
    const float* sfb = sf + (size_t)b * NTAP * HW;
    float* op = out + (size_t)bc * HW;
    for (int idx = t; idx < HW; idx += 256) {
        int i = idx / WW, j = idx - (idx / WW) * WW;
        float acc = 0.f;
        #pragma unroll
        for (int u = 0; u < KK; ++u)
            #pragma unroll
            for (int v = 0; v < KK; ++v) {
                int n = u * KK + v;
                acc += xt[(i + u) * 58 + (j + v)] * cf9[n] * sfb[(size_t)n * HW + idx];
            }
        op[idx] = acc;
    }
}

extern "C" void kernel_launch(void* const* d_in, const int* in_sizes, int n_in,
                              void* d_out, int out_size, void* d_ws, size_t ws_size,
                              hipStream_t stream) {
    const float* x      = (const float*)d_in[0];
    const float* w1     = (const float*)d_in[1];
    const float* b1     = (const float*)d_in[2];
    const float* w2     = (const float*)d_in[3];
    const float* b2     = (const float*)d_in[4];
    const float* ws     = (const float*)d_in[5];
    const float* bs     = (const float*)d_in[6];
    const float* fn_std = (const float*)d_in[7];
    float* out = (float*)d_out;

    float* wsf    = (float*)d_ws;
    float* pooled = wsf;                         // BB*CC            = 2048
    float* cf     = wsf + 2048;                  // BB*CKK           = 18432
    float* sf     = wsf + 2048 + 18432;          // BB*NTAP*HW       = 225792

    pool_kernel<<<BB * CC, 256, 0, stream>>>(x, pooled);
    sf_kernel<<<BB * HH, 64, 0, stream>>>(x, ws, bs, sf);
    mlp_kernel<<<BB, 256, 0, stream>>>(pooled, w1, b1, w2, b2, fn_std, cf);
    ddf_kernel<<<BB * CC, 256, 0, stream>>>(x, cf, sf, out);
}

// Round 2
// 141.440 us; speedup vs baseline: 1.2138x; 1.2138x over previous
//
#include <hip/hip_runtime.h>
#include <math.h>

#define BB   8
#define CC   256
#define HH   56
#define WW   56
#define KK   3
#define MIDN 51
#define NTAP (KK*KK)          // 9
#define CKK  (CC*NTAP)        // 2304
#define HW   (HH*WW)          // 3136
#define NCH  8                // channel chunks for sf reduction
#define CPC  (CC/NCH)         // 32 channels per chunk
#define PBLK 13               // ceil(3136/256)

// ---------------- pooled mean: one block per (b,c) plane ----------------
__global__ __launch_bounds__(256) void pool_kernel(const float* __restrict__ x,
                                                   float* __restrict__ pooled) {
    int bc = blockIdx.x;
    const float* xp = x + (size_t)bc * HW;
    int t = threadIdx.x;
    float s = 0.f;
    for (int idx = t; idx < HW; idx += 256) s += xp[idx];
    for (int off = 32; off > 0; off >>= 1) s += __shfl_down(s, off, 64);
    __shared__ float red[4];
    int wave = t >> 6, lane = t & 63;
    if (lane == 0) red[wave] = s;
    __syncthreads();
    if (t == 0) pooled[bc] = (red[0] + red[1] + red[2] + red[3]) * (1.0f / HW);
}

// ---------------- tiny MLP + per-channel filter norm: block per (b, 32-ch chunk) ----------------
__global__ __launch_bounds__(320) void mlp_kernel(const float* __restrict__ pooled,
                                                  const float* __restrict__ w1,
                                                  const float* __restrict__ b1,
                                                  const float* __restrict__ w2,
                                                  const float* __restrict__ b2,
                                                  const float* __restrict__ fn_std,
                                                  float* __restrict__ cf) {
    int blk = blockIdx.x;            // b*8 + chunk
    int b = blk >> 3, chunk = blk & 7;
    int c0 = chunk * 32;
    int t = threadIdx.x;
    __shared__ float ps[CC];
    __shared__ float y1[MIDN];
    __shared__ float y2s[32 * NTAP];
    if (t < CC) ps[t] = pooled[b * CC + t];
    __syncthreads();
    if (t < MIDN) {
        float acc = b1[t];
        const float* wr = w1 + t * CC;
        for (int c2 = 0; c2 < CC; ++c2) acc += ps[c2] * wr[c2];
        y1[t] = fmaxf(acc, 0.f);
    }
    __syncthreads();
    if (t < 32 * NTAP) {             // t -> (c_local, q)
        int cl = t / NTAP, q = t - cl * NTAP;
        int row = (c0 + cl) * NTAP + q;
        float acc = b2[row];
        const float* r = w2 + (size_t)row * MIDN;
        for (int m = 0; m < MIDN; ++m) acc += y1[m] * r[m];
        y2s[t] = acc;
    }
    __syncthreads();
    if (t < 32) {
        int c = c0 + t;
        float y2[NTAP];
        #pragma unroll
        for (int q = 0; q < NTAP; ++q) y2[q] = y2s[t * NTAP + q];
        float mean = 0.f;
        #pragma unroll
        for (int q = 0; q < NTAP; ++q) mean += y2[q];
        mean *= (1.f / NTAP);
        float var = 0.f;
        #pragma unroll
        for (int q = 0; q < NTAP; ++q) { float d = y2[q] - mean; var += d * d; }
        float inv = 1.f / (sqrtf(var * (1.f / (NTAP - 1))) + 1e-10f);
        #pragma unroll
        for (int q = 0; q < NTAP; ++q) {
            int idx = c * NTAP + q;
            cf[(size_t)b * CKK + idx] = (y2[q] - mean) * inv * fn_std[idx];
        }
    }
}

// ---------------- sf phase A: partial channel reduction ----------------
// grid: b * NCH * PBLK; block 256 threads = 256 consecutive pixels
__global__ __launch_bounds__(256) void sfA_kernel(const float* __restrict__ x,
                                                  const float* __restrict__ ws,
                                                  float* __restrict__ partial) {
    int blk = blockIdx.x;
    int pb = blk % PBLK;
    int tmp = blk / PBLK;
    int chunk = tmp % NCH;
    int b = tmp / NCH;
    int t = threadIdx.x;
    __shared__ float wss[NTAP][CPC];
    for (int idx = t; idx < NTAP * CPC; idx += 256) {
        int n = idx / CPC, c = idx - n * CPC;
        wss[n][c] = ws[n * CC + chunk * CPC + c];
    }
    __syncthreads();
    int p = pb * 256 + t;
    if (p >= HW) return;
    float acc[NTAP];
    #pragma unroll
    for (int n = 0; n < NTAP; ++n) acc[n] = 0.f;
    const float* xp = x + ((size_t)(b * CC + chunk * CPC)) * HW + p;
    for (int c = 0; c < CPC; ++c) {
        float xv = xp[(size_t)c * HW];
        #pragma unroll
        for (int n = 0; n < NTAP; ++n) acc[n] += xv * wss[n][c];
    }
    float* pp = partial + ((size_t)((b * NCH + chunk) * NTAP)) * HW + p;
    #pragma unroll
    for (int n = 0; n < NTAP; ++n) pp[(size_t)n * HW] = acc[n];
}

// ---------------- sf phase B: reduce chunks + softmax-free norm ----------------
// grid: b * PBLK
__global__ __launch_bounds__(256) void sfB_kernel(const float* __restrict__ partial,
                                                  const float* __restrict__ bs,
                                                  float* __restrict__ sf) {
    int blk = blockIdx.x;
    int b = blk / PBLK, pb = blk % PBLK;
    int p = pb * 256 + threadIdx.x;
    if (p >= HW) return;
    float acc[NTAP];
    #pragma unroll
    for (int n = 0; n < NTAP; ++n) acc[n] = bs[n];
    const float* pp = partial + ((size_t)(b * NCH)) * NTAP * HW + p;
    for (int chunk = 0; chunk < NCH; ++chunk)
        #pragma unroll
        for (int n = 0; n < NTAP; ++n)
            acc[n] += pp[((size_t)(chunk * NTAP + n)) * HW];
    float mean = 0.f;
    #pragma unroll
    for (int n = 0; n < NTAP; ++n) mean += acc[n];
    mean *= (1.f / NTAP);
    float var = 0.f;
    #pragma unroll
    for (int n = 0; n < NTAP; ++n) { float d = acc[n] - mean; var += d * d; }
    float inv = 0.47140452079103173f /       // GAIN/K = sqrt(2)/3
                (sqrtf(var * (1.f / (NTAP - 1))) + 1e-10f);
    #pragma unroll
    for (int n = 0; n < NTAP; ++n)
        sf[((size_t)(b * NTAP + n)) * HW + p] = (acc[n] - mean) * inv;
}

// ---------------- DDF apply: one block per (b,c) plane, LDS-staged 58x58 tile ----------------
__global__ __launch_bounds__(256) void ddf_kernel(const float* __restrict__ x,
                                                  const float* __restrict__ cf,
                                                  const float* __restrict__ sf,
                                                  float* __restrict__ out) {
    int bc = blockIdx.x;
    int b = bc / CC, c = bc % CC;
    int t = threadIdx.x;
    __shared__ float xt[58 * 58];
    for (int idx = t; idx < 58 * 58; idx += 256) xt[idx] = 0.f;
    __syncthreads();
    const float* xp = x + (size_t)bc * HW;
    for (int idx = t; idx < HW; idx += 256) {
        int r = idx / WW, col = idx - r * WW;
        xt[(r + 1) * 58 + col + 1] = xp[idx];
    }
    float cf9[NTAP];
    const float* cfp = cf + (size_t)b * CKK + c * NTAP;
    #pragma unroll
    for (int n = 0; n < NTAP; ++n) cf9[n] = cfp[n];
    __syncthreads();
    const float* sfb = sf + (size_t)b * NTAP * HW;
    float* op = out + (size_t)bc * HW;
    for (int idx = t; idx < HW; idx += 256) {
        int i = idx / WW, j = idx - (idx / WW) * WW;
        float acc = 0.f;
        #pragma unroll
        for (int u = 0; u < KK; ++u)
            #pragma unroll
            for (int v = 0; v < KK; ++v) {
                int n = u * KK + v;
                acc += xt[(i + u) * 58 + (j + v)] * cf9[n] * sfb[(size_t)n * HW + idx];
            }
        op[idx] = acc;
    }
}

extern "C" void kernel_launch(void* const* d_in, const int* in_sizes, int n_in,
                              void* d_out, int out_size, void* d_ws, size_t ws_size,
                              hipStream_t stream) {
    const float* x      = (const float*)d_in[0];
    const float* w1     = (const float*)d_in[1];
    const float* b1     = (const float*)d_in[2];
    const float* w2     = (const float*)d_in[3];
    const float* b2     = (const float*)d_in[4];
    const float* ws     = (const float*)d_in[5];
    const float* bs     = (const float*)d_in[6];
    const float* fn_std = (const float*)d_in[7];
    float* out = (float*)d_out;

    float* wsf     = (float*)d_ws;
    float* pooled  = wsf;                        // BB*CC                 = 2048
    float* cf      = wsf + 2048;                 // BB*CKK                = 18432
    float* sf      = wsf + 2048 + 18432;         // BB*NTAP*HW            = 225792
    float* partial = wsf + 2048 + 18432 + 225792;// BB*NCH*NTAP*HW        = 1806336

    pool_kernel<<<BB * CC, 256, 0, stream>>>(x, pooled);
    sfA_kernel<<<BB * NCH * PBLK, 256, 0, stream>>>(x, ws, partial);
    mlp_kernel<<<BB * NCH, 320, 0, stream>>>(pooled, w1, b1, w2, b2, fn_std, cf);
    sfB_kernel<<<BB * PBLK, 256, 0, stream>>>(partial, bs, sf);
    ddf_kernel<<<BB * CC, 256, 0, stream>>>(x, cf, sf, out);
}

// Round 3
// 134.109 us; speedup vs baseline: 1.2801x; 1.0547x over previous
//
#include <hip/hip_runtime.h>
#include <math.h>

#define BB   8
#define CC   256
#define HH   56
#define WW   56
#define KK   3
#define MIDN 51
#define NTAP (KK*KK)          // 9
#define CKK  (CC*NTAP)        // 2304
#define HW   (HH*WW)          // 3136
#define NCH  8                // channel chunks for sf reduction
#define CPC  (CC/NCH)         // 32 channels per chunk
#define PBLK 13               // ceil(3136/256)

// ============ K1: fused sf partial-reduction + pooled-mean partials ============
// grid: b * NCH * PBLK = 832 blocks, 256 threads (256 consecutive pixels).
// Writes: partial[(b*NCH+chunk)*9+n][p]  (ws-weighted channel-chunk sums)
//         poolpart[((b*NCH+chunk)*PBLK+pb)*32+cl]  (per-chunk-per-pixelblock channel sums)
__global__ __launch_bounds__(256) void k_sfpool(const float* __restrict__ x,
                                                const float* __restrict__ ws,
                                                float* __restrict__ partial,
                                                float* __restrict__ poolpart) {
    int blk = blockIdx.x;
    int pb = blk % PBLK;
    int tmp = blk / PBLK;
    int chunk = tmp % NCH;
    int b = tmp / NCH;
    int t = threadIdx.x;
    int wave = t >> 6, lane = t & 63;
    __shared__ float wss[NTAP][CPC];
    __shared__ float wsum[4][CPC];
    for (int idx = t; idx < NTAP * CPC; idx += 256) {
        int n = idx / CPC, c = idx - n * CPC;
        wss[n][c] = ws[n * CC + chunk * CPC + c];
    }
    __syncthreads();
    int p = pb * 256 + t;
    bool act = (p < HW);
    float acc[NTAP];
    #pragma unroll
    for (int n = 0; n < NTAP; ++n) acc[n] = 0.f;
    const float* xp = x + ((size_t)(b * CC + chunk * CPC)) * HW + p;
    for (int c = 0; c < CPC; ++c) {
        float xv = act ? xp[(size_t)c * HW] : 0.f;
        #pragma unroll
        for (int n = 0; n < NTAP; ++n) acc[n] += xv * wss[n][c];
        // wave-reduce xv for the pooled mean
        float s = xv;
        s += __shfl_down(s, 32, 64);
        s += __shfl_down(s, 16, 64);
        s += __shfl_down(s, 8, 64);
        s += __shfl_down(s, 4, 64);
        s += __shfl_down(s, 2, 64);
        s += __shfl_down(s, 1, 64);
        if (lane == 0) wsum[wave][c] = s;
    }
    __syncthreads();
    if (t < CPC) {
        float psum = wsum[0][t] + wsum[1][t] + wsum[2][t] + wsum[3][t];
        poolpart[((size_t)((b * NCH + chunk) * PBLK + pb)) * CPC + t] = psum;
    }
    if (act) {
        float* pp = partial + ((size_t)((b * NCH + chunk) * NTAP)) * HW + p;
        #pragma unroll
        for (int n = 0; n < NTAP; ++n) pp[(size_t)n * HW] = acc[n];
    }
}

// ============ K2: multi-role — blocks 0..63: MLP+cf ; blocks 64..167: sf reduce+norm ============
#define MLPBLK (BB*NCH)               // 64
#define W2CHUNK (CPC*NTAP*MIDN)       // 14688 floats per 32-channel chunk
__global__ __launch_bounds__(256) void k_mlp_sfB(const float* __restrict__ poolpart,
                                                 const float* __restrict__ w1,
                                                 const float* __restrict__ b1,
                                                 const float* __restrict__ w2,
                                                 const float* __restrict__ b2,
                                                 const float* __restrict__ fn_std,
                                                 const float* __restrict__ partial,
                                                 const float* __restrict__ bs,
                                                 float* __restrict__ cf,
                                                 float* __restrict__ sf) {
    __shared__ float smem[W2CHUNK + 256 + 64 + CPC * NTAP];  // 61.2 KB
    float* w2s = smem;                    // [14688]
    float* ps  = smem + W2CHUNK;          // [256]
    float* y1  = ps + 256;                // [64] (51 used)
    float* y2s = y1 + 64;                 // [288]
    int blk = blockIdx.x;
    int t = threadIdx.x;
    if (blk < MLPBLK) {
        int b = blk >> 3, chunk = blk & 7;
        int c0 = chunk * CPC;
        // stage this chunk's w2 rows (288 x 51) into LDS, float4-coalesced
        const float4* w2v = (const float4*)(w2 + (size_t)chunk * W2CHUNK);
        float4* w2s4 = (float4*)w2s;
        for (int i = t; i < W2CHUNK / 4; i += 256) w2s4[i] = w2v[i];
        // reduce pooled mean for ALL 256 channels of batch b
        {
            int chunkp = t >> 5, cl = t & 31;
            float s = 0.f;
            const float* pp = poolpart + ((size_t)(b * NCH + chunkp) * PBLK) * CPC + cl;
            #pragma unroll
            for (int pb = 0; pb < PBLK; ++pb) s += pp[pb * CPC];
            ps[t] = s * (1.0f / HW);
        }
        __syncthreads();
        if (t < MIDN) {
            float acc = b1[t];
            const float* wr = w1 + t * CC;
            for (int c2 = 0; c2 < CC; ++c2) acc += ps[c2] * wr[c2];
            y1[t] = fmaxf(acc, 0.f);
        }
        __syncthreads();
        #pragma unroll
        for (int base = 0; base < 512; base += 256) {
            int idx = base + t;                       // idx = cl*9+q
            if (idx < CPC * NTAP) {
                float acc = b2[c0 * NTAP + idx];
                const float* r = w2s + idx * MIDN;
                #pragma unroll 3
                for (int m = 0; m < MIDN; ++m) acc += y1[m] * r[m];
                y2s[idx] = acc;
            }
        }
        __syncthreads();
        if (t < CPC) {
            int c = c0 + t;
            float y2[NTAP];
            #pragma unroll
            for (int q = 0; q < NTAP; ++q) y2[q] = y2s[t * NTAP + q];
            float mean = 0.f;
            #pragma unroll
            for (int q = 0; q < NTAP; ++q) mean += y2[q];
            mean *= (1.f / NTAP);
            float var = 0.f;
            #pragma unroll
            for (int q = 0; q < NTAP; ++q) { float d = y2[q] - mean; var += d * d; }
            float inv = 1.f / (sqrtf(var * (1.f / (NTAP - 1))) + 1e-10f);
            #pragma unroll
            for (int q = 0; q < NTAP; ++q) {
                int idx = c * NTAP + q;
                cf[(size_t)b * CKK + idx] = (y2[q] - mean) * inv * fn_std[idx];
            }
        }
    } else {
        // sfB role: reduce channel-chunk partials + per-pixel tap normalization
        int sblk = blk - MLPBLK;                 // 0..103
        int b = sblk / PBLK, pb = sblk % PBLK;
        int p = pb * 256 + t;
        if (p >= HW) return;
        float acc[NTAP];
        #pragma unroll
        for (int n = 0; n < NTAP; ++n) acc[n] = bs[n];
        const float* pp = partial + ((size_t)(b * NCH)) * NTAP * HW + p;
        for (int chunk = 0; chunk < NCH; ++chunk)
            #pragma unroll
            for (int n = 0; n < NTAP; ++n)
                acc[n] += pp[((size_t)(chunk * NTAP + n)) * HW];
        float mean = 0.f;
        #pragma unroll
        for (int n = 0; n < NTAP; ++n) mean += acc[n];
        mean *= (1.f / NTAP);
        float var = 0.f;
        #pragma unroll
        for (int n = 0; n < NTAP; ++n) { float d = acc[n] - mean; var += d * d; }
        float inv = 0.47140452079103173f /       // GAIN/K = sqrt(2)/3
                    (sqrtf(var * (1.f / (NTAP - 1))) + 1e-10f);
        #pragma unroll
        for (int n = 0; n < NTAP; ++n)
            sf[((size_t)(b * NTAP + n)) * HW + p] = (acc[n] - mean) * inv;
    }
}

// ============ K3: DDF apply — one block per (b,c) plane, LDS 58x58 halo tile ============
__global__ __launch_bounds__(256) void k_ddf(const float* __restrict__ x,
                                             const float* __restrict__ cf,
                                             const float* __restrict__ sf,
                                             float* __restrict__ out) {
    int bc = blockIdx.x;
    int b = bc / CC, c = bc % CC;
    int t = threadIdx.x;
    __shared__ float xt[58 * 58];
    for (int idx = t; idx < 58 * 58; idx += 256) xt[idx] = 0.f;
    __syncthreads();
    const float* xp = x + (size_t)bc * HW;
    for (int idx = t; idx < HW; idx += 256) {
        int r = idx / WW, col = idx - r * WW;
        xt[(r + 1) * 58 + col + 1] = xp[idx];
    }
    float cf9[NTAP];
    const float* cfp = cf + (size_t)b * CKK + c * NTAP;
    #pragma unroll
    for (int n = 0; n < NTAP; ++n) cf9[n] = cfp[n];
    __syncthreads();
    const float* sfb = sf + (size_t)b * NTAP * HW;
    float* op = out + (size_t)bc * HW;
    for (int idx = t; idx < HW; idx += 256) {
        int i = idx / WW, j = idx - (idx / WW) * WW;
        float acc = 0.f;
        #pragma unroll
        for (int u = 0; u < KK; ++u)
            #pragma unroll
            for (int v = 0; v < KK; ++v) {
                int n = u * KK + v;
                acc += xt[(i + u) * 58 + (j + v)] * cf9[n] * sfb[(size_t)n * HW + idx];
            }
        op[idx] = acc;
    }
}

extern "C" void kernel_launch(void* const* d_in, const int* in_sizes, int n_in,
                              void* d_out, int out_size, void* d_ws, size_t ws_size,
                              hipStream_t stream) {
    const float* x      = (const float*)d_in[0];
    const float* w1     = (const float*)d_in[1];
    const float* b1     = (const float*)d_in[2];
    const float* w2     = (const float*)d_in[3];
    const float* b2     = (const float*)d_in[4];
    const float* ws     = (const float*)d_in[5];
    const float* bs     = (const float*)d_in[6];
    const float* fn_std = (const float*)d_in[7];
    float* out = (float*)d_out;

    float* wsf      = (float*)d_ws;
    float* cf       = wsf;                         // BB*CKK           = 18432
    float* sf       = cf + 18432;                  // BB*NTAP*HW       = 225792
    float* poolpart = sf + 225792;                 // 832*CPC          = 26624
    float* partial  = poolpart + 26624;            // BB*NCH*NTAP*HW   = 1806336

    k_sfpool<<<BB * NCH * PBLK, 256, 0, stream>>>(x, ws, partial, poolpart);
    k_mlp_sfB<<<MLPBLK + BB * PBLK, 256, 0, stream>>>(poolpart, w1, b1, w2, b2,
                                                      fn_std, partial, bs, cf, sf);
    k_ddf<<<BB * CC, 256, 0, stream>>>(x, cf, sf, out);
}

// Round 4
// 132.888 us; speedup vs baseline: 1.2919x; 1.0092x over previous
//
#include <hip/hip_runtime.h>
#include <math.h>

#define BB   8
#define CC   256
#define HH   56
#define WW   56
#define KK   3
#define MIDN 51
#define NTAP (KK*KK)          // 9
#define CKK  (CC*NTAP)        // 2304
#define HW   (HH*WW)          // 3136
#define NCH  8                // channel chunks for sf reduction
#define CPC  (CC/NCH)         // 32 channels per chunk
#define PBLK 13               // ceil(3136/256)
#define NCPB 2                // channels per ddf block (sf-reuse factor)

// ============ K1: fused sf partial-reduction + pooled-mean partials ============
__global__ __launch_bounds__(256) void k_sfpool(const float* __restrict__ x,
                                                const float* __restrict__ ws,
                                                float* __restrict__ partial,
                                                float* __restrict__ poolpart) {
    int blk = blockIdx.x;
    int pb = blk % PBLK;
    int tmp = blk / PBLK;
    int chunk = tmp % NCH;
    int b = tmp / NCH;
    int t = threadIdx.x;
    int wave = t >> 6, lane = t & 63;
    __shared__ float wss[NTAP][CPC];
    __shared__ float wsum[4][CPC];
    for (int idx = t; idx < NTAP * CPC; idx += 256) {
        int n = idx / CPC, c = idx - n * CPC;
        wss[n][c] = ws[n * CC + chunk * CPC + c];
    }
    __syncthreads();
    int p = pb * 256 + t;
    bool act = (p < HW);
    float acc[NTAP];
    #pragma unroll
    for (int n = 0; n < NTAP; ++n) acc[n] = 0.f;
    const float* xp = x + ((size_t)(b * CC + chunk * CPC)) * HW + p;
    for (int c = 0; c < CPC; ++c) {
        float xv = act ? xp[(size_t)c * HW] : 0.f;
        #pragma unroll
        for (int n = 0; n < NTAP; ++n) acc[n] += xv * wss[n][c];
        float s = xv;
        s += __shfl_down(s, 32, 64);
        s += __shfl_down(s, 16, 64);
        s += __shfl_down(s, 8, 64);
        s += __shfl_down(s, 4, 64);
        s += __shfl_down(s, 2, 64);
        s += __shfl_down(s, 1, 64);
        if (lane == 0) wsum[wave][c] = s;
    }
    __syncthreads();
    if (t < CPC) {
        float psum = wsum[0][t] + wsum[1][t] + wsum[2][t] + wsum[3][t];
        poolpart[((size_t)((b * NCH + chunk) * PBLK + pb)) * CPC + t] = psum;
    }
    if (act) {
        float* pp = partial + ((size_t)((b * NCH + chunk) * NTAP)) * HW + p;
        #pragma unroll
        for (int n = 0; n < NTAP; ++n) pp[(size_t)n * HW] = acc[n];
    }
}

// ============ K2: multi-role — blocks 0..63: MLP+cf ; blocks 64..167: sf reduce+norm ============
#define MLPBLK (BB*NCH)               // 64
#define W2CHUNK (CPC*NTAP*MIDN)       // 14688 floats per 32-channel chunk
__global__ __launch_bounds__(256) void k_mlp_sfB(const float* __restrict__ poolpart,
                                                 const float* __restrict__ w1,
                                                 const float* __restrict__ b1,
                                                 const float* __restrict__ w2,
                                                 const float* __restrict__ b2,
                                                 const float* __restrict__ fn_std,
                                                 const float* __restrict__ partial,
                                                 const float* __restrict__ bs,
                                                 float* __restrict__ cf,
                                                 float* __restrict__ sf) {
    __shared__ float smem[W2CHUNK + 256 + 64 + CPC * NTAP];  // 61.2 KB
    float* w2s = smem;                    // [14688]
    float* ps  = smem + W2CHUNK;          // [256]
    float* y1  = ps + 256;                // [64] (51 used)
    float* y2s = y1 + 64;                 // [288]
    int blk = blockIdx.x;
    int t = threadIdx.x;
    if (blk < MLPBLK) {
        int b = blk >> 3, chunk = blk & 7;
        int c0 = chunk * CPC;
        const float4* w2v = (const float4*)(w2 + (size_t)chunk * W2CHUNK);
        float4* w2s4 = (float4*)w2s;
        for (int i = t; i < W2CHUNK / 4; i += 256) w2s4[i] = w2v[i];
        {
            int chunkp = t >> 5, cl = t & 31;
            float s = 0.f;
            const float* pp = poolpart + ((size_t)(b * NCH + chunkp) * PBLK) * CPC + cl;
            #pragma unroll
            for (int pb = 0; pb < PBLK; ++pb) s += pp[pb * CPC];
            ps[t] = s * (1.0f / HW);
        }
        __syncthreads();
        if (t < MIDN) {
            float acc = b1[t];
            const float* wr = w1 + t * CC;
            for (int c2 = 0; c2 < CC; ++c2) acc += ps[c2] * wr[c2];
            y1[t] = fmaxf(acc, 0.f);
        }
        __syncthreads();
        #pragma unroll
        for (int base = 0; base < 512; base += 256) {
            int idx = base + t;                       // idx = cl*9+q
            if (idx < CPC * NTAP) {
                float acc = b2[c0 * NTAP + idx];
                const float* r = w2s + idx * MIDN;
                #pragma unroll 3
                for (int m = 0; m < MIDN; ++m) acc += y1[m] * r[m];
                y2s[idx] = acc;
            }
        }
        __syncthreads();
        if (t < CPC) {
            int c = c0 + t;
            float y2[NTAP];
            #pragma unroll
            for (int q = 0; q < NTAP; ++q) y2[q] = y2s[t * NTAP + q];
            float mean = 0.f;
            #pragma unroll
            for (int q = 0; q < NTAP; ++q) mean += y2[q];
            mean *= (1.f / NTAP);
            float var = 0.f;
            #pragma unroll
            for (int q = 0; q < NTAP; ++q) { float d = y2[q] - mean; var += d * d; }
            float inv = 1.f / (sqrtf(var * (1.f / (NTAP - 1))) + 1e-10f);
            #pragma unroll
            for (int q = 0; q < NTAP; ++q) {
                int idx = c * NTAP + q;
                cf[(size_t)b * CKK + idx] = (y2[q] - mean) * inv * fn_std[idx];
            }
        }
    } else {
        int sblk = blk - MLPBLK;                 // 0..103
        int b = sblk / PBLK, pb = sblk % PBLK;
        int p = pb * 256 + t;
        if (p >= HW) return;
        float acc[NTAP];
        #pragma unroll
        for (int n = 0; n < NTAP; ++n) acc[n] = bs[n];
        const float* pp = partial + ((size_t)(b * NCH)) * NTAP * HW + p;
        for (int chunk = 0; chunk < NCH; ++chunk)
            #pragma unroll
            for (int n = 0; n < NTAP; ++n)
                acc[n] += pp[((size_t)(chunk * NTAP + n)) * HW];
        float mean = 0.f;
        #pragma unroll
        for (int n = 0; n < NTAP; ++n) mean += acc[n];
        mean *= (1.f / NTAP);
        float var = 0.f;
        #pragma unroll
        for (int n = 0; n < NTAP; ++n) { float d = acc[n] - mean; var += d * d; }
        float inv = 0.47140452079103173f /       // GAIN/K = sqrt(2)/3
                    (sqrtf(var * (1.f / (NTAP - 1))) + 1e-10f);
        #pragma unroll
        for (int n = 0; n < NTAP; ++n)
            sf[((size_t)(b * NTAP + n)) * HW + p] = (acc[n] - mean) * inv;
    }
}

// ============ K3: DDF apply — NCPB channels per block; sf loaded once per pixel ============
// grid: BB * CC/NCPB = 1024 blocks. LDS: 2 halo tiles = 26.9 KB.
__global__ __launch_bounds__(256) void k_ddf(const float* __restrict__ x,
                                             const float* __restrict__ cf,
                                             const float* __restrict__ sf,
                                             float* __restrict__ out) {
    int blk = blockIdx.x;
    int b = blk / (CC / NCPB), cg = blk % (CC / NCPB);
    int c0 = cg * NCPB;
    int t = threadIdx.x;
    __shared__ float xt[NCPB][58 * 58];
    for (int idx = t; idx < NCPB * 58 * 58; idx += 256) ((float*)xt)[idx] = 0.f;
    __syncthreads();
    const float* xp = x + ((size_t)(b * CC + c0)) * HW;
    for (int idx = t; idx < HW; idx += 256) {
        int r = idx / WW, col = idx - r * WW;
        int o = (r + 1) * 58 + col + 1;
        xt[0][o] = xp[idx];
        xt[1][o] = xp[HW + idx];
    }
    float cf9[NCPB][NTAP];
    const float* cfp = cf + (size_t)b * CKK + c0 * NTAP;
    #pragma unroll
    for (int k = 0; k < NCPB; ++k)
        #pragma unroll
        for (int n = 0; n < NTAP; ++n) cf9[k][n] = cfp[k * NTAP + n];
    __syncthreads();
    const float* sfb = sf + (size_t)b * NTAP * HW;
    float* op = out + ((size_t)(b * CC + c0)) * HW;
    for (int idx = t; idx < HW; idx += 256) {
        int i = idx / WW, j = idx - i * WW;
        float s9[NTAP];
        #pragma unroll
        for (int n = 0; n < NTAP; ++n) s9[n] = sfb[(size_t)n * HW + idx];
        float acc0 = 0.f, acc1 = 0.f;
        #pragma unroll
        for (int u = 0; u < KK; ++u)
            #pragma unroll
            for (int v = 0; v < KK; ++v) {
                int n = u * KK + v;
                int o = (i + u) * 58 + (j + v);
                float xv0 = xt[0][o], xv1 = xt[1][o];
                acc0 += xv0 * (cf9[0][n] * s9[n]);
                acc1 += xv1 * (cf9[1][n] * s9[n]);
            }
        op[idx] = acc0;
        op[HW + idx] = acc1;
    }
}

extern "C" void kernel_launch(void* const* d_in, const int* in_sizes, int n_in,
                              void* d_out, int out_size, void* d_ws, size_t ws_size,
                              hipStream_t stream) {
    const float* x      = (const float*)d_in[0];
    const float* w1     = (const float*)d_in[1];
    const float* b1     = (const float*)d_in[2];
    const float* w2     = (const float*)d_in[3];
    const float* b2     = (const float*)d_in[4];
    const float* ws     = (const float*)d_in[5];
    const float* bs     = (const float*)d_in[6];
    const float* fn_std = (const float*)d_in[7];
    float* out = (float*)d_out;

    float* wsf      = (float*)d_ws;
    float* cf       = wsf;                         // BB*CKK           = 18432
    float* sf       = cf + 18432;                  // BB*NTAP*HW       = 225792
    float* poolpart = sf + 225792;                 // 832*CPC          = 26624
    float* partial  = poolpart + 26624;            // BB*NCH*NTAP*HW   = 1806336

    k_sfpool<<<BB * NCH * PBLK, 256, 0, stream>>>(x, ws, partial, poolpart);
    k_mlp_sfB<<<MLPBLK + BB * PBLK, 256, 0, stream>>>(poolpart, w1, b1, w2, b2,
                                                      fn_std, partial, bs, cf, sf);
    k_ddf<<<BB * (CC / NCPB), 256, 0, stream>>>(x, cf, sf, out);
}